// Round 15
// baseline (351.019 us; speedup 1.0000x reference)
//
#include <hip/hip_runtime.h>
#include <hip/hip_bf16.h>

using bf16 = __hip_bfloat16;
typedef __bf16 bf16x8v __attribute__((ext_vector_type(8)));
typedef float f32x4 __attribute__((ext_vector_type(4)));

static constexpr int SEQ = 2048;
static constexpr int DMODEL = 2048;
static constexpr int NHEADS = 16;
static constexpr int DQKC = 192;   // nope 128 + rope 64
static constexpr int DVC = 128;
static constexpr int DQC = 1536;
static constexpr int DCC = 512;
static constexpr int HQK = NHEADS * DQKC;  // 3072
static constexpr int HV = NHEADS * DVC;    // 2048
static constexpr int NKV = HQK + HV;       // 5120
static constexpr int NDOWN = DQC + DCC;    // 2048

typedef __attribute__((address_space(1))) const void* gas_ptr;
typedef __attribute__((address_space(3))) void* las_ptr;

__device__ __forceinline__ void g2l16(const void* g, void* l) {
  __builtin_amdgcn_global_load_lds((gas_ptr)g, (las_ptr)l, 16, 0, 0);
}

// ---------------- templated GEMM core: C[M,N] = alpha * A@Bt^T ----------------
// BM x BN block tile, 4 waves as 2x2 of (BM/2)x(BN/2), BK=32.
template <int BM, int BN>
__device__ __forceinline__ void gemm_core(
    const bf16* __restrict__ A, int lda,
    const bf16* __restrict__ Bt, int ldb,
    void* __restrict__ Cv, int ldc,
    int K, float alpha, int c_fp32, long tm, long tn, char* smem)
{
  constexpr int FM = BM / 32, FN = BN / 32;
  bf16* As = (bf16*)smem;              // [BM][32]
  char* Bsm = smem + BM * 64;          // [BN][32]
  bf16* Bs = (bf16*)Bsm;
  const int tid = threadIdx.x;
  const int w = tid >> 6, lane = tid & 63;
  const int wm = (w >> 1) * (BM / 2), wn = (w & 1) * (BN / 2);
  const int m0 = lane & 15, q8 = (lane >> 4) * 8;
  f32x4 acc[FM][FN] = {};
  for (int bk = 0; bk < K; bk += 32) {
#pragma unroll
    for (int i = 0; i < BM / 64; i++) {
      const int u = i * 256 + tid;
      g2l16(A + (tm + (u >> 2)) * (long)lda + bk + (u & 3) * 8, smem + u * 16);
    }
#pragma unroll
    for (int i = 0; i < BN / 64; i++) {
      const int u = i * 256 + tid;
      g2l16(Bt + (tn + (u >> 2)) * (long)ldb + bk + (u & 3) * 8, Bsm + u * 16);
    }
    __syncthreads();
    bf16x8v af[FM], bfv[FN];
#pragma unroll
    for (int i = 0; i < FM; i++)
      af[i] = *reinterpret_cast<const bf16x8v*>(&As[(wm + i * 16 + m0) * 32 + q8]);
#pragma unroll
    for (int i = 0; i < FN; i++)
      bfv[i] = *reinterpret_cast<const bf16x8v*>(&Bs[(wn + i * 16 + m0) * 32 + q8]);
#pragma unroll
    for (int mi = 0; mi < FM; mi++)
#pragma unroll
      for (int ni = 0; ni < FN; ni++)
        acc[mi][ni] = __builtin_amdgcn_mfma_f32_16x16x32_bf16(af[mi], bfv[ni], acc[mi][ni], 0, 0, 0);
    __syncthreads();
  }
  const int q4 = (lane >> 4) * 4;
  float* Cf = (float*)Cv;
  bf16* Cb = (bf16*)Cv;
#pragma unroll
  for (int mi = 0; mi < FM; mi++) {
#pragma unroll
    for (int r = 0; r < 4; r++) {
      const long row = tm + wm + mi * 16 + q4 + r;
#pragma unroll
      for (int ni = 0; ni < FN; ni++) {
        const long idx = row * ldc + tn + wn + ni * 16 + m0;
        const float v = acc[mi][ni][r] * alpha;
        if (c_fp32) Cf[idx] = v;
        else Cb[idx] = __float2bfloat16(v);
      }
    }
  }
}

// 64x128 tile GEMM for the projections: 512-block grids (2 blocks/CU).
// R10 post-mortem: 128x128 tiles here give 256-block grids (1 block/CU) and
// regressed total by >=11us — measured-good config is this one (R2: 333.6us).
__global__ __launch_bounds__(256) void gemm64(
    const bf16* __restrict__ A, int lda, const bf16* __restrict__ Bt, int ldb,
    void* __restrict__ Cv, int ldc, int K, float alpha, int c_fp32)
{
  __shared__ __align__(16) char smem[(64 + 128) * 64];
  gemm_core<64, 128>(A, lda, Bt, ldb, Cv, ldc, K, alpha, c_fp32,
                     (long)blockIdx.y * 64, (long)blockIdx.x * 128, smem);
}

// two independent GEMMs in one launch, 128x128 tiles, x-interleaved 3:5.
// q-up blocks run 48 K-iters, kv-up blocks 16 — contiguous x-ranges gave some
// CUs 4x48-iter blocks (1.7x the 112-iter/CU average; R10: occupancy 19.5%,
// 62us). Every 8 consecutive x-blocks now carry 3 q-up + 5 kv-up (24=8*3,
// 40=8*5 exact), so each CU's mix matches the global ratio. Order-only change.
__global__ __launch_bounds__(256) void gemm_dual(
    const bf16* __restrict__ A1, int lda1, const bf16* __restrict__ B1, int ldb1,
    void* __restrict__ C1, int ldc1, int K1, float alpha1,
    const bf16* __restrict__ A2, int lda2, const bf16* __restrict__ B2, int ldb2,
    void* __restrict__ C2, int ldc2, int K2)
{
  __shared__ __align__(16) char smem[(128 + 128) * 64];
  const int bx = blockIdx.x;           // 64 x-blocks: 8 groups of (3 q + 5 kv)
  const int g8 = bx >> 3, r8 = bx & 7;
  if (r8 < 3)
    gemm_core<128, 128>(A1, lda1, B1, ldb1, C1, ldc1, K1, alpha1, 0,
                        (long)blockIdx.y * 128, (long)(g8 * 3 + r8) * 128, smem);
  else
    gemm_core<128, 128>(A2, lda2, B2, ldb2, C2, ldc2, K2, 1.f, 0,
                        (long)blockIdx.y * 128, (long)(g8 * 5 + r8 - 3) * 128, smem);
}

// ------------- fused flash attention v6 (kt-parity wave groups) --------------
// 512 blocks x 512 thr (8 waves). Waves 0-3 = group 0 (even kt), waves 4-7 =
// group 1 (odd kt), SAME (q-tile, head): in-block split-K over the key stream,
// merged at the end via LDS log-sum-exp combine. Guarantees 2 working
// waves/SIMD for the whole kernel (v5 post-mortem: 1 wave/SIMD exposes the
// full latency chain). R10: flash_attn dropped out of top-5 (<62us, was 67.5).
// Dispatch: fid<256 -> tiles 31..16, else 15..0; CU round pairing (t, 31-t)
// gives every CU exactly ceil(nkt/2)+ceil(nkt'/2) = 12 iterations.
// Per-group LDS (disjoint; g = wave>>2):
//   Ks[g]: g*36864          96 keys x 24 fg : unit = key*24 + (fg ^ (key&7))
//   Vs[g]: 73728 + g*24576  128 dv x 12 kg  : unit = dv*12 + (kg ^ ((dv>>1)&3))
//   Ps[g]: 122880 + g*16384 64 rows x 16 k8 : unit = row*16 + (k8 ^ (row&15))
// All g2l16 guards are wave-uniform (divergent guard shifts the wave-uniform
// LDS base — round-5 bug).
__device__ __forceinline__ void fa_stage_k(
    const bf16* __restrict__ kvf, char* smem, int kbase, int key0, int h, int tg)
{
#pragma unroll
  for (int i = 0; i < 9; i++) {
    const int u = i * 256 + tg;
    const int key = u / 24;
    const int fg = (u - key * 24) ^ (key & 7);
    g2l16(kvf + (long)(key0 + key) * NKV + h * DQKC + fg * 8, smem + kbase + u * 16);
  }
}

__device__ __forceinline__ void fa_stage_v(
    const bf16* __restrict__ vT, char* smem, int vbase, int key0, int h, int tg)
{
#pragma unroll
  for (int i = 0; i < 6; i++) {
    const int u = i * 256 + tg;
    const int dv = u / 12;
    const int p = u - dv * 12;
    const int kgl = p ^ ((dv >> 1) & 3);
    g2l16(vT + (long)(h * DVC + dv) * SEQ + key0 + kgl * 8, smem + vbase + u * 16);
  }
}

__global__ __launch_bounds__(512) void flash_attn(
    const bf16* __restrict__ qf,   // [SEQ][HQK], 1/sqrt(dqk) pre-folded
    const bf16* __restrict__ kvf,  // [SEQ][NKV], k at col h*192
    const bf16* __restrict__ vT,   // [HV][SEQ]
    bf16* __restrict__ attn)       // [SEQ][HV]
{
  __shared__ __align__(16) char smem[155648];
  const int fid = blockIdx.x;
  const int tile = (fid < 256) ? (31 - (fid >> 4)) : (15 - ((fid - 256) >> 4));
  const int h = fid & 15;
  const int nkt = (tile * 64 + 63) / 96 + 1;  // 96-key tiles to cover diagonal
  const int J = (nkt + 1) >> 1;
  const int tid = threadIdx.x;
  const int w = tid >> 6, lane = tid & 63;
  const int g = w >> 2, wl = w & 3, tg = tid & 255;
  const int m0 = lane & 15, quad = lane >> 4;
  const int prow = wl * 16 + m0;
  const long qrow = (long)tile * 64 + prow;
  const int kbase = g * 36864;
  const int vbase = 73728 + g * 24576;
  const int pbase = 122880 + g * 16384;

  bf16x8v qfr[6];
#pragma unroll
  for (int s = 0; s < 6; s++)
    qfr[s] = *reinterpret_cast<const bf16x8v*>(
        &qf[qrow * HQK + h * DQKC + s * 32 + quad * 8]);

  f32x4 O[8] = {};
  float mrow = -1e30f, lrow = 0.f;

  if (g < nkt) {  // wave-uniform: group 1 skips when nkt==1
    fa_stage_k(kvf, smem, kbase, g * 96, h, tg);
    fa_stage_v(vT, smem, vbase, g * 96, h, tg);
  }
  __syncthreads();  // drains prologue staging

  for (int j = 0; j < J; ++j) {
    const int kt = 2 * j + g;
    const bool act = kt < nkt;        // wave-uniform
    const int key0 = kt * 96;

    // S^T = K @ Q^T : C row = key (quad*4+r), col = qrow (m0)
    f32x4 S[6] = {};
    if (act) {
#pragma unroll
      for (int s = 0; s < 6; s++) {
#pragma unroll
        for (int mi = 0; mi < 6; mi++) {
          const int kl = mi * 16 + m0;
          const int idx = kl * 24 + ((s * 4 + quad) ^ (m0 & 7));
          const bf16x8v kb = *reinterpret_cast<const bf16x8v*>(smem + kbase + idx * 16);
          S[mi] = __builtin_amdgcn_mfma_f32_16x16x32_bf16(kb, qfr[s], S[mi], 0, 0, 0);
        }
      }
    }
    __syncthreads();  // B1: all K reads of this iter done (both groups)

    if (kt + 2 < nkt)  // wave-uniform; lands during softmax+PV, drains at B2
      fa_stage_k(kvf, smem, kbase, key0 + 192, h, tg);

    if (act) {
      if (key0 + 95 > tile * 64) {  // tile touches/passes the diagonal
#pragma unroll
        for (int mi = 0; mi < 6; mi++)
#pragma unroll
          for (int r = 0; r < 4; r++)
            if (key0 + mi * 16 + quad * 4 + r > qrow) S[mi][r] = -1e30f;
      }

      // wave-local online softmax (row = m0; partners at lane^16, lane^32)
      float fm = -1e30f;
#pragma unroll
      for (int mi = 0; mi < 6; mi++)
#pragma unroll
        for (int r = 0; r < 4; r++) fm = fmaxf(fm, S[mi][r]);
      fm = fmaxf(fm, __shfl_xor(fm, 16, 64));
      fm = fmaxf(fm, __shfl_xor(fm, 32, 64));
      const float newm = fmaxf(mrow, fm);
      const float alph = __expf(mrow - newm);
      mrow = newm;
      float ps = 0.f;
#pragma unroll
      for (int mi = 0; mi < 6; mi++)
#pragma unroll
        for (int r = 0; r < 4; r++) {
          const float p = __expf(S[mi][r] - newm);
          S[mi][r] = p;
          ps += p;
        }
      ps += __shfl_xor(ps, 16, 64);
      ps += __shfl_xor(ps, 32, 64);
      lrow = lrow * alph + ps;

      // P -> LDS (b64, wave-private rows; own region, no barrier needed)
#pragma unroll
      for (int mi = 0; mi < 6; mi++) {
        const int k8 = mi * 2 + (quad >> 1);
        const int idx = prow * 16 + (k8 ^ (m0 & 15));
        unsigned short b[4];
#pragma unroll
        for (int r = 0; r < 4; r++) {
          const bf16 t = __float2bfloat16(S[mi][r]);
          b[r] = *reinterpret_cast<const unsigned short*>(&t);
        }
        *reinterpret_cast<uint2*>(smem + pbase + idx * 16 + (quad & 1) * 8) =
            make_uint2((unsigned)b[0] | ((unsigned)b[1] << 16),
                       (unsigned)b[2] | ((unsigned)b[3] << 16));
      }
      float aO[4];
#pragma unroll
      for (int r = 0; r < 4; r++) aO[r] = __shfl(alph, quad * 4 + r, 16);
#pragma unroll
      for (int ni = 0; ni < 8; ni++)
#pragma unroll
        for (int r = 0; r < 4; r++) O[ni][r] *= aO[r];

      // O += P @ V
#pragma unroll
      for (int ks = 0; ks < 3; ks++) {
        const int idxp = prow * 16 + ((ks * 4 + quad) ^ (m0 & 15));
        const bf16x8v pa = *reinterpret_cast<const bf16x8v*>(smem + pbase + idxp * 16);
#pragma unroll
        for (int ni = 0; ni < 8; ni++) {
          const int dv = ni * 16 + m0;
          const int idxv = dv * 12 + ((ks * 4 + quad) ^ ((dv >> 1) & 3));
          const bf16x8v vb = *reinterpret_cast<const bf16x8v*>(smem + vbase + idxv * 16);
          O[ni] = __builtin_amdgcn_mfma_f32_16x16x32_bf16(pa, vb, O[ni], 0, 0, 0);
        }
      }
    }
    __syncthreads();  // B2: all V reads done; drains K-stage

    if (kt + 2 < nkt)  // lands during next iter's QK, drains at next B1
      fa_stage_v(vT, smem, vbase, key0 + 192, h, tg);
  }

  // -------- merge group 1 (odd kt) into group 0 (even kt), then write -------
  float* Om  = (float*)smem;             // [64] m1   (K0 region, dead)
  float* Ol  = (float*)(smem + 256);     // [64] l1
  float* O1s = (float*)(smem + 122880);  // [64][128] (P0+P1 regions, dead)
  if (g == 1) {
    if (quad == 0) { Om[prow] = mrow; Ol[prow] = lrow; }
#pragma unroll
    for (int ni = 0; ni < 8; ni++)
#pragma unroll
      for (int r = 0; r < 4; r++)
        O1s[(wl * 16 + quad * 4 + r) * 128 + ni * 16 + m0] = O[ni][r];
  }
  __syncthreads();
  if (g == 0) {
    float a0[4], a1[4];
#pragma unroll
    for (int r = 0; r < 4; r++) {
      const int row = quad * 4 + r;
      const float m0r = __shfl(mrow, row, 16);
      const float l0r = __shfl(lrow, row, 16);
      const float m1r = Om[wl * 16 + row];
      const float l1r = Ol[wl * 16 + row];
      const float mm = fmaxf(m0r, m1r);
      const float e0 = __expf(m0r - mm), e1 = __expf(m1r - mm);
      const float iv = 1.f / (l0r * e0 + l1r * e1);
      a0[r] = e0 * iv;
      a1[r] = e1 * iv;
    }
#pragma unroll
    for (int ni = 0; ni < 8; ni++)
#pragma unroll
      for (int r = 0; r < 4; r++) {
        const float v = O[ni][r] * a0[r] +
                        O1s[(wl * 16 + quad * 4 + r) * 128 + ni * 16 + m0] * a1[r];
        attn[((long)tile * 64 + wl * 16 + quad * 4 + r) * HV + h * DVC + ni * 16 + m0] =
            __float2bfloat16(v);
      }
  }
}

// ---------------- small kernels ----------------
__device__ __forceinline__ float tofl(float x) { return x; }
__device__ __forceinline__ float tofl(bf16 x) { return __bfloat162float(x); }

template <typename TIN>
__global__ __launch_bounds__(256) void transpose_cast(const TIN* __restrict__ in,
                                                      bf16* __restrict__ out,
                                                      int inStride, int outStride) {
  __shared__ float t[32][33];
  const int bx = blockIdx.x * 32, by = blockIdx.y * 32;
  const int tx = threadIdx.x, ty = threadIdx.y;
#pragma unroll
  for (int j = 0; j < 32; j += 8)
    t[ty + j][tx] = tofl(in[(long)(by + ty + j) * inStride + bx + tx]);
  __syncthreads();
#pragma unroll
  for (int j = 0; j < 32; j += 8)
    out[(long)(bx + ty + j) * outStride + by + tx] = __float2bfloat16(t[tx][ty + j]);
}

struct TPar { const float* src; bf16* dst; int C; int R; int gw; int nblk; };

// six independent fp32->bf16 transposes in one launch
__global__ __launch_bounds__(256) void transpose6(TPar a, TPar b, TPar c,
                                                  TPar d, TPar e, TPar f) {
  int blk = blockIdx.x;
  TPar p;
  if (blk < a.nblk) p = a;
  else { blk -= a.nblk;
  if (blk < b.nblk) p = b;
  else { blk -= b.nblk;
  if (blk < c.nblk) p = c;
  else { blk -= c.nblk;
  if (blk < d.nblk) p = d;
  else { blk -= d.nblk;
  if (blk < e.nblk) p = e;
  else { blk -= e.nblk; p = f; } } } } }
  const int bx = (blk % p.gw) * 32, by = (blk / p.gw) * 32;
  __shared__ float t[32][33];
  const int tx = threadIdx.x, ty = threadIdx.y;
#pragma unroll
  for (int j = 0; j < 32; j += 8)
    t[ty + j][tx] = p.src[(long)(by + ty + j) * p.C + bx + tx];
  __syncthreads();
#pragma unroll
  for (int j = 0; j < 32; j += 8)
    p.dst[(long)(bx + ty + j) * p.R + by + tx] = __float2bfloat16(t[tx][ty + j]);
}

__global__ __launch_bounds__(256) void cast_f32_bf16(const float* __restrict__ in,
                                                     bf16* __restrict__ out, int n4) {
  int i = blockIdx.x * 256 + threadIdx.x;
  if (i < n4) {
    const float4 v = ((const float4*)in)[i];
    out[i * 4 + 0] = __float2bfloat16(v.x);
    out[i * 4 + 1] = __float2bfloat16(v.y);
    out[i * 4 + 2] = __float2bfloat16(v.z);
    out[i * 4 + 3] = __float2bfloat16(v.w);
  }
}

__global__ __launch_bounds__(256) void rope_qk(bf16* __restrict__ q, bf16* __restrict__ k) {
  const int idx = blockIdx.x * 256 + threadIdx.x;  // SEQ*NHEADS*32 threads
  const int i = idx & 31;
  const int h = (idx >> 5) & 15;
  const int l = idx >> 9;
  const float inv = powf(10000.f, -(float)i * (1.f / 32.f));
  float s, c;
  sincosf((float)l * inv, &s, &c);
  const long qb = (long)l * HQK + h * DQKC + 128;
  const long kb = (long)l * NKV + h * DQKC + 128;
  {
    float x0 = __bfloat162float(q[qb + i]);
    float x1 = __bfloat162float(q[qb + i + 32]);
    q[qb + i] = __float2bfloat16(x0 * c - x1 * s);
    q[qb + i + 32] = __float2bfloat16(x1 * c + x0 * s);
  }
  {
    float x0 = __bfloat162float(k[kb + i]);
    float x1 = __bfloat162float(k[kb + i + 32]);
    k[kb + i] = __float2bfloat16(x0 * c - x1 * s);
    k[kb + i + 32] = __float2bfloat16(x1 * c + x0 * s);
  }
}

extern "C" void kernel_launch(void* const* d_in, const int* in_sizes, int n_in,
                              void* d_out, int out_size, void* d_ws, size_t ws_size,
                              hipStream_t stream) {
  const float* hs      = (const float*)d_in[0];
  // d_in[1] attention_mask: exact causal mask; applied analytically.
  const float* Wq_down = (const float*)d_in[2];
  const float* Wq_up   = (const float*)d_in[3];
  const float* Wkv_down= (const float*)d_in[4];
  const float* Wk_up   = (const float*)d_in[5];
  const float* Wv_up   = (const float*)d_in[6];
  const float* Wo      = (const float*)d_in[7];

  char* p = (char*)d_ws;
  auto alloc = [&](long elems) {
    bf16* r = (bf16*)p;
    p += ((elems * 2 + 255) / 256) * 256;
    return r;
  };
  bf16* hsb   = alloc((long)SEQ * DMODEL);
  bf16* W1T   = alloc((long)NDOWN * DMODEL);
  bf16* WquT  = alloc((long)HQK * DQC);
  bf16* WkvuT = alloc((long)NKV * DCC);
  bf16* WoT   = alloc((long)DMODEL * HV);
  bf16* qdc   = alloc((long)SEQ * NDOWN);
  bf16* qf    = alloc((long)SEQ * HQK);
  bf16* kvf   = alloc((long)SEQ * NKV);
  bf16* vT    = alloc((long)HV * SEQ);
  bf16* attn  = alloc((long)SEQ * HV);

  const float scale = 0.07216878364870323f;  // 1/sqrt(192), folded into q

  const dim3 b256(256);
  const dim3 tb(32, 8);
  cast_f32_bf16<<<dim3(SEQ * DMODEL / 4 / 256), b256, 0, stream>>>(hs, hsb, SEQ * DMODEL / 4);

  TPar ta{Wq_down,  W1T,                      DQC,    DMODEL, DQC / 32,    (DQC / 32) * (DMODEL / 32)};
  TPar tb2{Wkv_down, W1T + (long)DQC * DMODEL, DCC,    DMODEL, DCC / 32,    (DCC / 32) * (DMODEL / 32)};
  TPar tc{Wq_up,    WquT,                     HQK,    DQC,    HQK / 32,    (HQK / 32) * (DQC / 32)};
  TPar td{Wk_up,    WkvuT,                    HQK,    DCC,    HQK / 32,    (HQK / 32) * (DCC / 32)};
  TPar te{Wv_up,    WkvuT + (long)HQK * DCC,  HV,     DCC,    HV / 32,     (HV / 32) * (DCC / 32)};
  TPar tf{Wo,       WoT,                      DMODEL, HV,     DMODEL / 32, (DMODEL / 32) * (HV / 32)};
  const int tblk = ta.nblk + tb2.nblk + tc.nblk + td.nblk + te.nblk + tf.nblk;
  transpose6<<<dim3(tblk), tb, 0, stream>>>(ta, tb2, tc, td, te, tf);

  // fused down-projection: [qd | ckv] = hsb @ [Wq_down | Wkv_down], 64x128
  gemm64<<<dim3(NDOWN / 128, SEQ / 64), b256, 0, stream>>>(
      hsb, DMODEL, W1T, DMODEL, qdc, NDOWN, DMODEL, 1.f, 0);

  // q up (scale folded) + fused k/v up, 128x128 tiles, 3:5 x-interleaved
  gemm_dual<<<dim3(64, SEQ / 128), b256, 0, stream>>>(
      qdc, NDOWN, WquT, DQC, qf, HQK, DQC, scale,
      qdc + DQC, NDOWN, WkvuT, DCC, kvf, NKV, DCC);

  rope_qk<<<dim3(SEQ * NHEADS * 32 / 256), b256, 0, stream>>>(qf, kvf);
  transpose_cast<bf16><<<dim3(HV / 32, SEQ / 32), tb, 0, stream>>>(kvf + HQK, vT, NKV, SEQ);

  // fused attention v6: 512 blocks x 512 thr, kt-parity wave groups
  flash_attn<<<dim3(512), dim3(512), 0, stream>>>(qf, kvf, vT, attn);

  // output projection (fp32 out), 64x128
  gemm64<<<dim3(DMODEL / 128, SEQ / 64), b256, 0, stream>>>(
      attn, HV, WoT, HV, d_out, DMODEL, HV, 1.f, 1);
}

// Round 16
// 330.228 us; speedup vs baseline: 1.0630x; 1.0630x over previous
//
#include <hip/hip_runtime.h>
#include <hip/hip_bf16.h>

using bf16 = __hip_bfloat16;
typedef __bf16 bf16x8v __attribute__((ext_vector_type(8)));
typedef float f32x4 __attribute__((ext_vector_type(4)));

static constexpr int SEQ = 2048;
static constexpr int DMODEL = 2048;
static constexpr int NHEADS = 16;
static constexpr int DQKC = 192;   // nope 128 + rope 64
static constexpr int DVC = 128;
static constexpr int DQC = 1536;
static constexpr int DCC = 512;
static constexpr int HQK = NHEADS * DQKC;  // 3072
static constexpr int HV = NHEADS * DVC;    // 2048
static constexpr int NKV = HQK + HV;       // 5120
static constexpr int NDOWN = DQC + DCC;    // 2048

typedef __attribute__((address_space(1))) const void* gas_ptr;
typedef __attribute__((address_space(3))) void* las_ptr;

__device__ __forceinline__ void g2l16(const void* g, void* l) {
  __builtin_amdgcn_global_load_lds((gas_ptr)g, (las_ptr)l, 16, 0, 0);
}

// ---------------- templated GEMM core: C[M,N] = alpha * A@Bt^T ----------------
// BM x BN block tile, 4 waves as 2x2 of (BM/2)x(BN/2), BK=32.
template <int BM, int BN>
__device__ __forceinline__ void gemm_core(
    const bf16* __restrict__ A, int lda,
    const bf16* __restrict__ Bt, int ldb,
    void* __restrict__ Cv, int ldc,
    int K, float alpha, int c_fp32, long tm, long tn, char* smem)
{
  constexpr int FM = BM / 32, FN = BN / 32;
  bf16* As = (bf16*)smem;              // [BM][32]
  char* Bsm = smem + BM * 64;          // [BN][32]
  bf16* Bs = (bf16*)Bsm;
  const int tid = threadIdx.x;
  const int w = tid >> 6, lane = tid & 63;
  const int wm = (w >> 1) * (BM / 2), wn = (w & 1) * (BN / 2);
  const int m0 = lane & 15, q8 = (lane >> 4) * 8;
  f32x4 acc[FM][FN] = {};
  for (int bk = 0; bk < K; bk += 32) {
#pragma unroll
    for (int i = 0; i < BM / 64; i++) {
      const int u = i * 256 + tid;
      g2l16(A + (tm + (u >> 2)) * (long)lda + bk + (u & 3) * 8, smem + u * 16);
    }
#pragma unroll
    for (int i = 0; i < BN / 64; i++) {
      const int u = i * 256 + tid;
      g2l16(Bt + (tn + (u >> 2)) * (long)ldb + bk + (u & 3) * 8, Bsm + u * 16);
    }
    __syncthreads();
    bf16x8v af[FM], bfv[FN];
#pragma unroll
    for (int i = 0; i < FM; i++)
      af[i] = *reinterpret_cast<const bf16x8v*>(&As[(wm + i * 16 + m0) * 32 + q8]);
#pragma unroll
    for (int i = 0; i < FN; i++)
      bfv[i] = *reinterpret_cast<const bf16x8v*>(&Bs[(wn + i * 16 + m0) * 32 + q8]);
#pragma unroll
    for (int mi = 0; mi < FM; mi++)
#pragma unroll
      for (int ni = 0; ni < FN; ni++)
        acc[mi][ni] = __builtin_amdgcn_mfma_f32_16x16x32_bf16(af[mi], bfv[ni], acc[mi][ni], 0, 0, 0);
    __syncthreads();
  }
  const int q4 = (lane >> 4) * 4;
  float* Cf = (float*)Cv;
  bf16* Cb = (bf16*)Cv;
#pragma unroll
  for (int mi = 0; mi < FM; mi++) {
#pragma unroll
    for (int r = 0; r < 4; r++) {
      const long row = tm + wm + mi * 16 + q4 + r;
#pragma unroll
      for (int ni = 0; ni < FN; ni++) {
        const long idx = row * ldc + tn + wn + ni * 16 + m0;
        const float v = acc[mi][ni][r] * alpha;
        if (c_fp32) Cf[idx] = v;
        else Cb[idx] = __float2bfloat16(v);
      }
    }
  }
}

// 64x128 tile GEMM for the projections: 512-block grids (2 blocks/CU).
// R10/R15: 128x128 here (256-block grids) regressed ~21us total; this config
// is measured-good (R2: 333.6us, R15 recovered ~21us vs R10).
__global__ __launch_bounds__(256) void gemm64(
    const bf16* __restrict__ A, int lda, const bf16* __restrict__ Bt, int ldb,
    void* __restrict__ Cv, int ldc, int K, float alpha, int c_fp32)
{
  __shared__ __align__(16) char smem[(64 + 128) * 64];
  gemm_core<64, 128>(A, lda, Bt, ldb, Cv, ldc, K, alpha, c_fp32,
                     (long)blockIdx.y * 64, (long)blockIdx.x * 128, smem);
}

// two independent GEMMs in one launch (grid.x split at nx1), 128x128 tiles,
// CONTIGUOUS x-ranges. R15 post-mortem: 3:5 interleave regressed 62->89.8us
// (MfmaUtil 18.9->12.7, occ 19.5->13) — the HW scheduler dynamically backfills
// 1024-block grids, so static per-CU mixing is unnecessary and hurt L2/stall
// behavior. This contiguous form is the measured-good one (R10: 62us).
__global__ __launch_bounds__(256) void gemm_dual(
    const bf16* __restrict__ A1, int lda1, const bf16* __restrict__ B1, int ldb1,
    void* __restrict__ C1, int ldc1, int K1, float alpha1, int nx1,
    const bf16* __restrict__ A2, int lda2, const bf16* __restrict__ B2, int ldb2,
    void* __restrict__ C2, int ldc2, int K2)
{
  __shared__ __align__(16) char smem[(128 + 128) * 64];
  if ((int)blockIdx.x < nx1)
    gemm_core<128, 128>(A1, lda1, B1, ldb1, C1, ldc1, K1, alpha1, 0,
                        (long)blockIdx.y * 128, (long)blockIdx.x * 128, smem);
  else
    gemm_core<128, 128>(A2, lda2, B2, ldb2, C2, ldc2, K2, 1.f, 0,
                        (long)blockIdx.y * 128, (long)((int)blockIdx.x - nx1) * 128, smem);
}

// ------------- fused flash attention v6 (kt-parity wave groups) --------------
// 512 blocks x 512 thr (8 waves). Waves 0-3 = group 0 (even kt), waves 4-7 =
// group 1 (odd kt), SAME (q-tile, head): in-block split-K over the key stream,
// merged at the end via LDS log-sum-exp combine. Guarantees 2 working
// waves/SIMD for the whole kernel (v5 post-mortem: 1 wave/SIMD exposes the
// full latency chain). R10: flash_attn dropped out of top-5 (<62us, was 67.5).
// Dispatch: fid<256 -> tiles 31..16, else 15..0; CU round pairing (t, 31-t)
// gives every CU exactly ceil(nkt/2)+ceil(nkt'/2) = 12 iterations.
// Per-group LDS (disjoint; g = wave>>2):
//   Ks[g]: g*36864          96 keys x 24 fg : unit = key*24 + (fg ^ (key&7))
//   Vs[g]: 73728 + g*24576  128 dv x 12 kg  : unit = dv*12 + (kg ^ ((dv>>1)&3))
//   Ps[g]: 122880 + g*16384 64 rows x 16 k8 : unit = row*16 + (k8 ^ (row&15))
// All g2l16 guards are wave-uniform (divergent guard shifts the wave-uniform
// LDS base — round-5 bug).
__device__ __forceinline__ void fa_stage_k(
    const bf16* __restrict__ kvf, char* smem, int kbase, int key0, int h, int tg)
{
#pragma unroll
  for (int i = 0; i < 9; i++) {
    const int u = i * 256 + tg;
    const int key = u / 24;
    const int fg = (u - key * 24) ^ (key & 7);
    g2l16(kvf + (long)(key0 + key) * NKV + h * DQKC + fg * 8, smem + kbase + u * 16);
  }
}

__device__ __forceinline__ void fa_stage_v(
    const bf16* __restrict__ vT, char* smem, int vbase, int key0, int h, int tg)
{
#pragma unroll
  for (int i = 0; i < 6; i++) {
    const int u = i * 256 + tg;
    const int dv = u / 12;
    const int p = u - dv * 12;
    const int kgl = p ^ ((dv >> 1) & 3);
    g2l16(vT + (long)(h * DVC + dv) * SEQ + key0 + kgl * 8, smem + vbase + u * 16);
  }
}

__global__ __launch_bounds__(512) void flash_attn(
    const bf16* __restrict__ qf,   // [SEQ][HQK], 1/sqrt(dqk) pre-folded
    const bf16* __restrict__ kvf,  // [SEQ][NKV], k at col h*192
    const bf16* __restrict__ vT,   // [HV][SEQ]
    bf16* __restrict__ attn)       // [SEQ][HV]
{
  __shared__ __align__(16) char smem[155648];
  const int fid = blockIdx.x;
  const int tile = (fid < 256) ? (31 - (fid >> 4)) : (15 - ((fid - 256) >> 4));
  const int h = fid & 15;
  const int nkt = (tile * 64 + 63) / 96 + 1;  // 96-key tiles to cover diagonal
  const int J = (nkt + 1) >> 1;
  const int tid = threadIdx.x;
  const int w = tid >> 6, lane = tid & 63;
  const int g = w >> 2, wl = w & 3, tg = tid & 255;
  const int m0 = lane & 15, quad = lane >> 4;
  const int prow = wl * 16 + m0;
  const long qrow = (long)tile * 64 + prow;
  const int kbase = g * 36864;
  const int vbase = 73728 + g * 24576;
  const int pbase = 122880 + g * 16384;

  bf16x8v qfr[6];
#pragma unroll
  for (int s = 0; s < 6; s++)
    qfr[s] = *reinterpret_cast<const bf16x8v*>(
        &qf[qrow * HQK + h * DQKC + s * 32 + quad * 8]);

  f32x4 O[8] = {};
  float mrow = -1e30f, lrow = 0.f;

  if (g < nkt) {  // wave-uniform: group 1 skips when nkt==1
    fa_stage_k(kvf, smem, kbase, g * 96, h, tg);
    fa_stage_v(vT, smem, vbase, g * 96, h, tg);
  }
  __syncthreads();  // drains prologue staging

  for (int j = 0; j < J; ++j) {
    const int kt = 2 * j + g;
    const bool act = kt < nkt;        // wave-uniform
    const int key0 = kt * 96;

    // S^T = K @ Q^T : C row = key (quad*4+r), col = qrow (m0)
    f32x4 S[6] = {};
    if (act) {
#pragma unroll
      for (int s = 0; s < 6; s++) {
#pragma unroll
        for (int mi = 0; mi < 6; mi++) {
          const int kl = mi * 16 + m0;
          const int idx = kl * 24 + ((s * 4 + quad) ^ (m0 & 7));
          const bf16x8v kb = *reinterpret_cast<const bf16x8v*>(smem + kbase + idx * 16);
          S[mi] = __builtin_amdgcn_mfma_f32_16x16x32_bf16(kb, qfr[s], S[mi], 0, 0, 0);
        }
      }
    }
    __syncthreads();  // B1: all K reads of this iter done (both groups)

    if (kt + 2 < nkt)  // wave-uniform; lands during softmax+PV, drains at B2
      fa_stage_k(kvf, smem, kbase, key0 + 192, h, tg);

    if (act) {
      if (key0 + 95 > tile * 64) {  // tile touches/passes the diagonal
#pragma unroll
        for (int mi = 0; mi < 6; mi++)
#pragma unroll
          for (int r = 0; r < 4; r++)
            if (key0 + mi * 16 + quad * 4 + r > qrow) S[mi][r] = -1e30f;
      }

      // wave-local online softmax (row = m0; partners at lane^16, lane^32)
      float fm = -1e30f;
#pragma unroll
      for (int mi = 0; mi < 6; mi++)
#pragma unroll
        for (int r = 0; r < 4; r++) fm = fmaxf(fm, S[mi][r]);
      fm = fmaxf(fm, __shfl_xor(fm, 16, 64));
      fm = fmaxf(fm, __shfl_xor(fm, 32, 64));
      const float newm = fmaxf(mrow, fm);
      const float alph = __expf(mrow - newm);
      mrow = newm;
      float ps = 0.f;
#pragma unroll
      for (int mi = 0; mi < 6; mi++)
#pragma unroll
        for (int r = 0; r < 4; r++) {
          const float p = __expf(S[mi][r] - newm);
          S[mi][r] = p;
          ps += p;
        }
      ps += __shfl_xor(ps, 16, 64);
      ps += __shfl_xor(ps, 32, 64);
      lrow = lrow * alph + ps;

      // P -> LDS (b64, wave-private rows; own region, no barrier needed)
#pragma unroll
      for (int mi = 0; mi < 6; mi++) {
        const int k8 = mi * 2 + (quad >> 1);
        const int idx = prow * 16 + (k8 ^ (m0 & 15));
        unsigned short b[4];
#pragma unroll
        for (int r = 0; r < 4; r++) {
          const bf16 t = __float2bfloat16(S[mi][r]);
          b[r] = *reinterpret_cast<const unsigned short*>(&t);
        }
        *reinterpret_cast<uint2*>(smem + pbase + idx * 16 + (quad & 1) * 8) =
            make_uint2((unsigned)b[0] | ((unsigned)b[1] << 16),
                       (unsigned)b[2] | ((unsigned)b[3] << 16));
      }
      float aO[4];
#pragma unroll
      for (int r = 0; r < 4; r++) aO[r] = __shfl(alph, quad * 4 + r, 16);
#pragma unroll
      for (int ni = 0; ni < 8; ni++)
#pragma unroll
        for (int r = 0; r < 4; r++) O[ni][r] *= aO[r];

      // O += P @ V
#pragma unroll
      for (int ks = 0; ks < 3; ks++) {
        const int idxp = prow * 16 + ((ks * 4 + quad) ^ (m0 & 15));
        const bf16x8v pa = *reinterpret_cast<const bf16x8v*>(smem + pbase + idxp * 16);
#pragma unroll
        for (int ni = 0; ni < 8; ni++) {
          const int dv = ni * 16 + m0;
          const int idxv = dv * 12 + ((ks * 4 + quad) ^ ((dv >> 1) & 3));
          const bf16x8v vb = *reinterpret_cast<const bf16x8v*>(smem + vbase + idxv * 16);
          O[ni] = __builtin_amdgcn_mfma_f32_16x16x32_bf16(pa, vb, O[ni], 0, 0, 0);
        }
      }
    }
    __syncthreads();  // B2: all V reads done; drains K-stage

    if (kt + 2 < nkt)  // lands during next iter's QK, drains at next B1
      fa_stage_v(vT, smem, vbase, key0 + 192, h, tg);
  }

  // -------- merge group 1 (odd kt) into group 0 (even kt), then write -------
  float* Om  = (float*)smem;             // [64] m1   (K0 region, dead)
  float* Ol  = (float*)(smem + 256);     // [64] l1
  float* O1s = (float*)(smem + 122880);  // [64][128] (P0+P1 regions, dead)
  if (g == 1) {
    if (quad == 0) { Om[prow] = mrow; Ol[prow] = lrow; }
#pragma unroll
    for (int ni = 0; ni < 8; ni++)
#pragma unroll
      for (int r = 0; r < 4; r++)
        O1s[(wl * 16 + quad * 4 + r) * 128 + ni * 16 + m0] = O[ni][r];
  }
  __syncthreads();
  if (g == 0) {
    float a0[4], a1[4];
#pragma unroll
    for (int r = 0; r < 4; r++) {
      const int row = quad * 4 + r;
      const float m0r = __shfl(mrow, row, 16);
      const float l0r = __shfl(lrow, row, 16);
      const float m1r = Om[wl * 16 + row];
      const float l1r = Ol[wl * 16 + row];
      const float mm = fmaxf(m0r, m1r);
      const float e0 = __expf(m0r - mm), e1 = __expf(m1r - mm);
      const float iv = 1.f / (l0r * e0 + l1r * e1);
      a0[r] = e0 * iv;
      a1[r] = e1 * iv;
    }
#pragma unroll
    for (int ni = 0; ni < 8; ni++)
#pragma unroll
      for (int r = 0; r < 4; r++) {
        const float v = O[ni][r] * a0[r] +
                        O1s[(wl * 16 + quad * 4 + r) * 128 + ni * 16 + m0] * a1[r];
        attn[((long)tile * 64 + wl * 16 + quad * 4 + r) * HV + h * DVC + ni * 16 + m0] =
            __float2bfloat16(v);
      }
  }
}

// ---------------- small kernels ----------------
__device__ __forceinline__ float tofl(float x) { return x; }
__device__ __forceinline__ float tofl(bf16 x) { return __bfloat162float(x); }

template <typename TIN>
__global__ __launch_bounds__(256) void transpose_cast(const TIN* __restrict__ in,
                                                      bf16* __restrict__ out,
                                                      int inStride, int outStride) {
  __shared__ float t[32][33];
  const int bx = blockIdx.x * 32, by = blockIdx.y * 32;
  const int tx = threadIdx.x, ty = threadIdx.y;
#pragma unroll
  for (int j = 0; j < 32; j += 8)
    t[ty + j][tx] = tofl(in[(long)(by + ty + j) * inStride + bx + tx]);
  __syncthreads();
#pragma unroll
  for (int j = 0; j < 32; j += 8)
    out[(long)(bx + ty + j) * outStride + by + tx] = __float2bfloat16(t[tx][ty + j]);
}

struct TPar { const float* src; bf16* dst; int C; int R; int gw; int nblk; };

// six independent fp32->bf16 transposes in one launch
__global__ __launch_bounds__(256) void transpose6(TPar a, TPar b, TPar c,
                                                  TPar d, TPar e, TPar f) {
  int blk = blockIdx.x;
  TPar p;
  if (blk < a.nblk) p = a;
  else { blk -= a.nblk;
  if (blk < b.nblk) p = b;
  else { blk -= b.nblk;
  if (blk < c.nblk) p = c;
  else { blk -= c.nblk;
  if (blk < d.nblk) p = d;
  else { blk -= d.nblk;
  if (blk < e.nblk) p = e;
  else { blk -= e.nblk; p = f; } } } } }
  const int bx = (blk % p.gw) * 32, by = (blk / p.gw) * 32;
  __shared__ float t[32][33];
  const int tx = threadIdx.x, ty = threadIdx.y;
#pragma unroll
  for (int j = 0; j < 32; j += 8)
    t[ty + j][tx] = p.src[(long)(by + ty + j) * p.C + bx + tx];
  __syncthreads();
#pragma unroll
  for (int j = 0; j < 32; j += 8)
    p.dst[(long)(bx + ty + j) * p.R + by + tx] = __float2bfloat16(t[tx][ty + j]);
}

__global__ __launch_bounds__(256) void cast_f32_bf16(const float* __restrict__ in,
                                                     bf16* __restrict__ out, int n4) {
  int i = blockIdx.x * 256 + threadIdx.x;
  if (i < n4) {
    const float4 v = ((const float4*)in)[i];
    out[i * 4 + 0] = __float2bfloat16(v.x);
    out[i * 4 + 1] = __float2bfloat16(v.y);
    out[i * 4 + 2] = __float2bfloat16(v.z);
    out[i * 4 + 3] = __float2bfloat16(v.w);
  }
}

__global__ __launch_bounds__(256) void rope_qk(bf16* __restrict__ q, bf16* __restrict__ k) {
  const int idx = blockIdx.x * 256 + threadIdx.x;  // SEQ*NHEADS*32 threads
  const int i = idx & 31;
  const int h = (idx >> 5) & 15;
  const int l = idx >> 9;
  const float inv = powf(10000.f, -(float)i * (1.f / 32.f));
  float s, c;
  sincosf((float)l * inv, &s, &c);
  const long qb = (long)l * HQK + h * DQKC + 128;
  const long kb = (long)l * NKV + h * DQKC + 128;
  {
    float x0 = __bfloat162float(q[qb + i]);
    float x1 = __bfloat162float(q[qb + i + 32]);
    q[qb + i] = __float2bfloat16(x0 * c - x1 * s);
    q[qb + i + 32] = __float2bfloat16(x1 * c + x0 * s);
  }
  {
    float x0 = __bfloat162float(k[kb + i]);
    float x1 = __bfloat162float(k[kb + i + 32]);
    k[kb + i] = __float2bfloat16(x0 * c - x1 * s);
    k[kb + i + 32] = __float2bfloat16(x1 * c + x0 * s);
  }
}

extern "C" void kernel_launch(void* const* d_in, const int* in_sizes, int n_in,
                              void* d_out, int out_size, void* d_ws, size_t ws_size,
                              hipStream_t stream) {
  const float* hs      = (const float*)d_in[0];
  // d_in[1] attention_mask: exact causal mask; applied analytically.
  const float* Wq_down = (const float*)d_in[2];
  const float* Wq_up   = (const float*)d_in[3];
  const float* Wkv_down= (const float*)d_in[4];
  const float* Wk_up   = (const float*)d_in[5];
  const float* Wv_up   = (const float*)d_in[6];
  const float* Wo      = (const float*)d_in[7];

  char* p = (char*)d_ws;
  auto alloc = [&](long elems) {
    bf16* r = (bf16*)p;
    p += ((elems * 2 + 255) / 256) * 256;
    return r;
  };
  bf16* hsb   = alloc((long)SEQ * DMODEL);
  bf16* W1T   = alloc((long)NDOWN * DMODEL);
  bf16* WquT  = alloc((long)HQK * DQC);
  bf16* WkvuT = alloc((long)NKV * DCC);
  bf16* WoT   = alloc((long)DMODEL * HV);
  bf16* qdc   = alloc((long)SEQ * NDOWN);
  bf16* qf    = alloc((long)SEQ * HQK);
  bf16* kvf   = alloc((long)SEQ * NKV);
  bf16* vT    = alloc((long)HV * SEQ);
  bf16* attn  = alloc((long)SEQ * HV);

  const float scale = 0.07216878364870323f;  // 1/sqrt(192), folded into q

  const dim3 b256(256);
  const dim3 tb(32, 8);
  cast_f32_bf16<<<dim3(SEQ * DMODEL / 4 / 256), b256, 0, stream>>>(hs, hsb, SEQ * DMODEL / 4);

  TPar ta{Wq_down,  W1T,                      DQC,    DMODEL, DQC / 32,    (DQC / 32) * (DMODEL / 32)};
  TPar tb2{Wkv_down, W1T + (long)DQC * DMODEL, DCC,    DMODEL, DCC / 32,    (DCC / 32) * (DMODEL / 32)};
  TPar tc{Wq_up,    WquT,                     HQK,    DQC,    HQK / 32,    (HQK / 32) * (DQC / 32)};
  TPar td{Wk_up,    WkvuT,                    HQK,    DCC,    HQK / 32,    (HQK / 32) * (DCC / 32)};
  TPar te{Wv_up,    WkvuT + (long)HQK * DCC,  HV,     DCC,    HV / 32,     (HV / 32) * (DCC / 32)};
  TPar tf{Wo,       WoT,                      DMODEL, HV,     DMODEL / 32, (DMODEL / 32) * (HV / 32)};
  const int tblk = ta.nblk + tb2.nblk + tc.nblk + td.nblk + te.nblk + tf.nblk;
  transpose6<<<dim3(tblk), tb, 0, stream>>>(ta, tb2, tc, td, te, tf);

  // fused down-projection: [qd | ckv] = hsb @ [Wq_down | Wkv_down], 64x128
  gemm64<<<dim3(NDOWN / 128, SEQ / 64), b256, 0, stream>>>(
      hsb, DMODEL, W1T, DMODEL, qdc, NDOWN, DMODEL, 1.f, 0);

  // q up (scale folded) + fused k/v up, 128x128 tiles, contiguous split (R10)
  gemm_dual<<<dim3(HQK / 128 + NKV / 128, SEQ / 128), b256, 0, stream>>>(
      qdc, NDOWN, WquT, DQC, qf, HQK, DQC, scale, HQK / 128,
      qdc + DQC, NDOWN, WkvuT, DCC, kvf, NKV, DCC);

  rope_qk<<<dim3(SEQ * NHEADS * 32 / 256), b256, 0, stream>>>(qf, kvf);
  transpose_cast<bf16><<<dim3(HV / 32, SEQ / 32), tb, 0, stream>>>(kvf + HQK, vT, NKV, SEQ);

  // fused attention v6: 512 blocks x 512 thr, kt-parity wave groups
  flash_attn<<<dim3(512), dim3(512), 0, stream>>>(qf, kvf, vT, attn);

  // output projection (fp32 out), 64x128
  gemm64<<<dim3(DMODEL / 128, SEQ / 64), b256, 0, stream>>>(
      attn, HV, WoT, HV, d_out, DMODEL, HV, 1.f, 1);
}

// Round 17
// 317.487 us; speedup vs baseline: 1.1056x; 1.0401x over previous
//
#include <hip/hip_runtime.h>
#include <hip/hip_bf16.h>

using bf16 = __hip_bfloat16;
typedef __bf16 bf16x8v __attribute__((ext_vector_type(8)));
typedef float f32x4 __attribute__((ext_vector_type(4)));

static constexpr int SEQ = 2048;
static constexpr int DMODEL = 2048;
static constexpr int NHEADS = 16;
static constexpr int DQKC = 192;   // nope 128 + rope 64
static constexpr int DVC = 128;
static constexpr int DQC = 1536;
static constexpr int DCC = 512;
static constexpr int HQK = NHEADS * DQKC;  // 3072
static constexpr int HV = NHEADS * DVC;    // 2048
static constexpr int NKV = HQK + HV;       // 5120
static constexpr int NDOWN = DQC + DCC;    // 2048

typedef __attribute__((address_space(1))) const void* gas_ptr;
typedef __attribute__((address_space(3))) void* las_ptr;

__device__ __forceinline__ void g2l16(const void* g, void* l) {
  __builtin_amdgcn_global_load_lds((gas_ptr)g, (las_ptr)l, 16, 0, 0);
}

// ---------------- templated GEMM core: C[M,N] = alpha * A@Bt^T ----------------
// BM x BN block tile, 4 waves as 2x2 of (BM/2)x(BN/2), BK=32.
template <int BM, int BN>
__device__ __forceinline__ void gemm_core(
    const bf16* __restrict__ A, int lda,
    const bf16* __restrict__ Bt, int ldb,
    void* __restrict__ Cv, int ldc,
    int K, float alpha, int c_fp32, long tm, long tn, char* smem)
{
  constexpr int FM = BM / 32, FN = BN / 32;
  bf16* As = (bf16*)smem;              // [BM][32]
  char* Bsm = smem + BM * 64;          // [BN][32]
  bf16* Bs = (bf16*)Bsm;
  const int tid = threadIdx.x;
  const int w = tid >> 6, lane = tid & 63;
  const int wm = (w >> 1) * (BM / 2), wn = (w & 1) * (BN / 2);
  const int m0 = lane & 15, q8 = (lane >> 4) * 8;
  f32x4 acc[FM][FN] = {};
  for (int bk = 0; bk < K; bk += 32) {
#pragma unroll
    for (int i = 0; i < BM / 64; i++) {
      const int u = i * 256 + tid;
      g2l16(A + (tm + (u >> 2)) * (long)lda + bk + (u & 3) * 8, smem + u * 16);
    }
#pragma unroll
    for (int i = 0; i < BN / 64; i++) {
      const int u = i * 256 + tid;
      g2l16(Bt + (tn + (u >> 2)) * (long)ldb + bk + (u & 3) * 8, Bsm + u * 16);
    }
    __syncthreads();
    bf16x8v af[FM], bfv[FN];
#pragma unroll
    for (int i = 0; i < FM; i++)
      af[i] = *reinterpret_cast<const bf16x8v*>(&As[(wm + i * 16 + m0) * 32 + q8]);
#pragma unroll
    for (int i = 0; i < FN; i++)
      bfv[i] = *reinterpret_cast<const bf16x8v*>(&Bs[(wn + i * 16 + m0) * 32 + q8]);
#pragma unroll
    for (int mi = 0; mi < FM; mi++)
#pragma unroll
      for (int ni = 0; ni < FN; ni++)
        acc[mi][ni] = __builtin_amdgcn_mfma_f32_16x16x32_bf16(af[mi], bfv[ni], acc[mi][ni], 0, 0, 0);
    __syncthreads();
  }
  const int q4 = (lane >> 4) * 4;
  float* Cf = (float*)Cv;
  bf16* Cb = (bf16*)Cv;
#pragma unroll
  for (int mi = 0; mi < FM; mi++) {
#pragma unroll
    for (int r = 0; r < 4; r++) {
      const long row = tm + wm + mi * 16 + q4 + r;
#pragma unroll
      for (int ni = 0; ni < FN; ni++) {
        const long idx = row * ldc + tn + wn + ni * 16 + m0;
        const float v = acc[mi][ni][r] * alpha;
        if (c_fp32) Cf[idx] = v;
        else Cb[idx] = __float2bfloat16(v);
      }
    }
  }
}

// 64x128 tile GEMM for the projections: 512-block grids (2 blocks/CU).
// R10/R15: 128x128 here (256-block grids) regressed ~21us total; this config
// is measured-good (R2: 333.6us, R16: 330.2us).
__global__ __launch_bounds__(256) void gemm64(
    const bf16* __restrict__ A, int lda, const bf16* __restrict__ Bt, int ldb,
    void* __restrict__ Cv, int ldc, int K, float alpha, int c_fp32)
{
  __shared__ __align__(16) char smem[(64 + 128) * 64];
  gemm_core<64, 128>(A, lda, Bt, ldb, Cv, ldc, K, alpha, c_fp32,
                     (long)blockIdx.y * 64, (long)blockIdx.x * 128, smem);
}

// two independent GEMMs in one launch (grid.x split at nx1), 128x128 tiles,
// CONTIGUOUS x-ranges. R15: 3:5 interleave regressed 62->89.8us — the HW
// scheduler dynamically backfills 1024-block grids; static mixing hurt L2.
// This contiguous form is measured-good (R10/R16: 61-62us).
__global__ __launch_bounds__(256) void gemm_dual(
    const bf16* __restrict__ A1, int lda1, const bf16* __restrict__ B1, int ldb1,
    void* __restrict__ C1, int ldc1, int K1, float alpha1, int nx1,
    const bf16* __restrict__ A2, int lda2, const bf16* __restrict__ B2, int ldb2,
    void* __restrict__ C2, int ldc2, int K2)
{
  __shared__ __align__(16) char smem[(128 + 128) * 64];
  if ((int)blockIdx.x < nx1)
    gemm_core<128, 128>(A1, lda1, B1, ldb1, C1, ldc1, K1, alpha1, 0,
                        (long)blockIdx.y * 128, (long)blockIdx.x * 128, smem);
  else
    gemm_core<128, 128>(A2, lda2, B2, ldb2, C2, ldc2, K2, 1.f, 0,
                        (long)blockIdx.y * 128, (long)((int)blockIdx.x - nx1) * 128, smem);
}

// ------------- fused flash attention v6.1 (kt-parity wave groups) ------------
// 512 blocks x 512 thr (8 waves). Waves 0-3 = group 0 (even kt), waves 4-7 =
// group 1 (odd kt), SAME (q-tile, head): in-block split-K over the key stream,
// merged at the end via LDS log-sum-exp combine. 2 working waves/SIMD for the
// whole kernel. R16: steady-state <61us (only the cold ord-0 dispatch shows).
// v6.1 adds T13 defer-max: skip the O-rescale when the per-tile max grew <=8
// (P bounded by e^8; bf16 relative precision is scale-invariant; group merge
// already handles arbitrary per-group m). Guide: +5% attn, data-independent.
// Per-group LDS (disjoint; g = wave>>2):
//   Ks[g]: g*36864          96 keys x 24 fg : unit = key*24 + (fg ^ (key&7))
//   Vs[g]: 73728 + g*24576  128 dv x 12 kg  : unit = dv*12 + (kg ^ ((dv>>1)&3))
//   Ps[g]: 122880 + g*16384 64 rows x 16 k8 : unit = row*16 + (k8 ^ (row&15))
// All g2l16 guards are wave-uniform (divergent guard shifts the wave-uniform
// LDS base — round-5 bug).
__device__ __forceinline__ void fa_stage_k(
    const bf16* __restrict__ kvf, char* smem, int kbase, int key0, int h, int tg)
{
#pragma unroll
  for (int i = 0; i < 9; i++) {
    const int u = i * 256 + tg;
    const int key = u / 24;
    const int fg = (u - key * 24) ^ (key & 7);
    g2l16(kvf + (long)(key0 + key) * NKV + h * DQKC + fg * 8, smem + kbase + u * 16);
  }
}

__device__ __forceinline__ void fa_stage_v(
    const bf16* __restrict__ vT, char* smem, int vbase, int key0, int h, int tg)
{
#pragma unroll
  for (int i = 0; i < 6; i++) {
    const int u = i * 256 + tg;
    const int dv = u / 12;
    const int p = u - dv * 12;
    const int kgl = p ^ ((dv >> 1) & 3);
    g2l16(vT + (long)(h * DVC + dv) * SEQ + key0 + kgl * 8, smem + vbase + u * 16);
  }
}

__global__ __launch_bounds__(512) void flash_attn(
    const bf16* __restrict__ qf,   // [SEQ][HQK], 1/sqrt(dqk) pre-folded
    const bf16* __restrict__ kvf,  // [SEQ][NKV], k at col h*192
    const bf16* __restrict__ vT,   // [HV][SEQ]
    bf16* __restrict__ attn)       // [SEQ][HV]
{
  __shared__ __align__(16) char smem[155648];
  const int fid = blockIdx.x;
  const int tile = (fid < 256) ? (31 - (fid >> 4)) : (15 - ((fid - 256) >> 4));
  const int h = fid & 15;
  const int nkt = (tile * 64 + 63) / 96 + 1;  // 96-key tiles to cover diagonal
  const int J = (nkt + 1) >> 1;
  const int tid = threadIdx.x;
  const int w = tid >> 6, lane = tid & 63;
  const int g = w >> 2, wl = w & 3, tg = tid & 255;
  const int m0 = lane & 15, quad = lane >> 4;
  const int prow = wl * 16 + m0;
  const long qrow = (long)tile * 64 + prow;
  const int kbase = g * 36864;
  const int vbase = 73728 + g * 24576;
  const int pbase = 122880 + g * 16384;

  bf16x8v qfr[6];
#pragma unroll
  for (int s = 0; s < 6; s++)
    qfr[s] = *reinterpret_cast<const bf16x8v*>(
        &qf[qrow * HQK + h * DQKC + s * 32 + quad * 8]);

  f32x4 O[8] = {};
  float mrow = -1e30f, lrow = 0.f;

  if (g < nkt) {  // wave-uniform: group 1 skips when nkt==1
    fa_stage_k(kvf, smem, kbase, g * 96, h, tg);
    fa_stage_v(vT, smem, vbase, g * 96, h, tg);
  }
  __syncthreads();  // drains prologue staging

  for (int j = 0; j < J; ++j) {
    const int kt = 2 * j + g;
    const bool act = kt < nkt;        // wave-uniform
    const int key0 = kt * 96;

    // S^T = K @ Q^T : C row = key (quad*4+r), col = qrow (m0)
    f32x4 S[6] = {};
    if (act) {
#pragma unroll
      for (int s = 0; s < 6; s++) {
#pragma unroll
        for (int mi = 0; mi < 6; mi++) {
          const int kl = mi * 16 + m0;
          const int idx = kl * 24 + ((s * 4 + quad) ^ (m0 & 7));
          const bf16x8v kb = *reinterpret_cast<const bf16x8v*>(smem + kbase + idx * 16);
          S[mi] = __builtin_amdgcn_mfma_f32_16x16x32_bf16(kb, qfr[s], S[mi], 0, 0, 0);
        }
      }
    }
    __syncthreads();  // B1: all K reads of this iter done (both groups)

    if (kt + 2 < nkt)  // wave-uniform; lands during softmax+PV, drains at B2
      fa_stage_k(kvf, smem, kbase, key0 + 192, h, tg);

    if (act) {
      if (key0 + 95 > tile * 64) {  // tile touches/passes the diagonal
#pragma unroll
        for (int mi = 0; mi < 6; mi++)
#pragma unroll
          for (int r = 0; r < 4; r++)
            if (key0 + mi * 16 + quad * 4 + r > qrow) S[mi][r] = -1e30f;
      }

      // wave-local online softmax (row = m0; partners at lane^16, lane^32)
      float fm = -1e30f;
#pragma unroll
      for (int mi = 0; mi < 6; mi++)
#pragma unroll
        for (int r = 0; r < 4; r++) fm = fmaxf(fm, S[mi][r]);
      fm = fmaxf(fm, __shfl_xor(fm, 16, 64));
      fm = fmaxf(fm, __shfl_xor(fm, 32, 64));
      // T13 defer-max: keep stale mrow while growth <= 8 (P bounded by e^8)
      const bool skip = __all(fm <= mrow + 8.f) != 0;
      float alph = 1.f;
      if (!skip) {
        const float newm = fmaxf(mrow, fm);
        alph = __expf(mrow - newm);
        mrow = newm;
      }
      float ps = 0.f;
#pragma unroll
      for (int mi = 0; mi < 6; mi++)
#pragma unroll
        for (int r = 0; r < 4; r++) {
          const float p = __expf(S[mi][r] - mrow);
          S[mi][r] = p;
          ps += p;
        }
      ps += __shfl_xor(ps, 16, 64);
      ps += __shfl_xor(ps, 32, 64);
      lrow = lrow * alph + ps;

      // P -> LDS (b64, wave-private rows; own region, no barrier needed)
#pragma unroll
      for (int mi = 0; mi < 6; mi++) {
        const int k8 = mi * 2 + (quad >> 1);
        const int idx = prow * 16 + (k8 ^ (m0 & 15));
        unsigned short b[4];
#pragma unroll
        for (int r = 0; r < 4; r++) {
          const bf16 t = __float2bfloat16(S[mi][r]);
          b[r] = *reinterpret_cast<const unsigned short*>(&t);
        }
        *reinterpret_cast<uint2*>(smem + pbase + idx * 16 + (quad & 1) * 8) =
            make_uint2((unsigned)b[0] | ((unsigned)b[1] << 16),
                       (unsigned)b[2] | ((unsigned)b[3] << 16));
      }
      if (!skip) {
        float aO[4];
#pragma unroll
        for (int r = 0; r < 4; r++) aO[r] = __shfl(alph, quad * 4 + r, 16);
#pragma unroll
        for (int ni = 0; ni < 8; ni++)
#pragma unroll
          for (int r = 0; r < 4; r++) O[ni][r] *= aO[r];
      }

      // O += P @ V
#pragma unroll
      for (int ks = 0; ks < 3; ks++) {
        const int idxp = prow * 16 + ((ks * 4 + quad) ^ (m0 & 15));
        const bf16x8v pa = *reinterpret_cast<const bf16x8v*>(smem + pbase + idxp * 16);
#pragma unroll
        for (int ni = 0; ni < 8; ni++) {
          const int dv = ni * 16 + m0;
          const int idxv = dv * 12 + ((ks * 4 + quad) ^ ((dv >> 1) & 3));
          const bf16x8v vb = *reinterpret_cast<const bf16x8v*>(smem + vbase + idxv * 16);
          O[ni] = __builtin_amdgcn_mfma_f32_16x16x32_bf16(pa, vb, O[ni], 0, 0, 0);
        }
      }
    }
    __syncthreads();  // B2: all V reads done; drains K-stage

    if (kt + 2 < nkt)  // lands during next iter's QK, drains at next B1
      fa_stage_v(vT, smem, vbase, key0 + 192, h, tg);
  }

  // -------- merge group 1 (odd kt) into group 0 (even kt), then write -------
  float* Om  = (float*)smem;             // [64] m1   (K0 region, dead)
  float* Ol  = (float*)(smem + 256);     // [64] l1
  float* O1s = (float*)(smem + 122880);  // [64][128] (P0+P1 regions, dead)
  if (g == 1) {
    if (quad == 0) { Om[prow] = mrow; Ol[prow] = lrow; }
#pragma unroll
    for (int ni = 0; ni < 8; ni++)
#pragma unroll
      for (int r = 0; r < 4; r++)
        O1s[(wl * 16 + quad * 4 + r) * 128 + ni * 16 + m0] = O[ni][r];
  }
  __syncthreads();
  if (g == 0) {
    float a0[4], a1[4];
#pragma unroll
    for (int r = 0; r < 4; r++) {
      const int row = quad * 4 + r;
      const float m0r = __shfl(mrow, row, 16);
      const float l0r = __shfl(lrow, row, 16);
      const float m1r = Om[wl * 16 + row];
      const float l1r = Ol[wl * 16 + row];
      const float mm = fmaxf(m0r, m1r);
      const float e0 = __expf(m0r - mm), e1 = __expf(m1r - mm);
      const float iv = 1.f / (l0r * e0 + l1r * e1);
      a0[r] = e0 * iv;
      a1[r] = e1 * iv;
    }
#pragma unroll
    for (int ni = 0; ni < 8; ni++)
#pragma unroll
      for (int r = 0; r < 4; r++) {
        const float v = O[ni][r] * a0[r] +
                        O1s[(wl * 16 + quad * 4 + r) * 128 + ni * 16 + m0] * a1[r];
        attn[((long)tile * 64 + wl * 16 + quad * 4 + r) * HV + h * DVC + ni * 16 + m0] =
            __float2bfloat16(v);
      }
  }
}

// ---------------- fused preprocessing ----------------
struct TPar { const float* src; bf16* dst; int C; int R; int gw; int nblk; };

// cast_f32_bf16 (blocks < castBlks) + six fp32->bf16 transposes, one launch.
// Block-uniform branch; cast blocks return before any barrier.
__global__ __launch_bounds__(256) void prep_fused(
    const float* __restrict__ hs, bf16* __restrict__ hsb, int n4, int castBlks,
    TPar a, TPar b, TPar c, TPar d, TPar e, TPar f)
{
  int blk = blockIdx.x;
  if (blk < castBlks) {
    const int i = blk * 256 + threadIdx.x;
    if (i < n4) {
      const float4 v = ((const float4*)hs)[i];
      hsb[i * 4 + 0] = __float2bfloat16(v.x);
      hsb[i * 4 + 1] = __float2bfloat16(v.y);
      hsb[i * 4 + 2] = __float2bfloat16(v.z);
      hsb[i * 4 + 3] = __float2bfloat16(v.w);
    }
    return;
  }
  blk -= castBlks;
  TPar p;
  if (blk < a.nblk) p = a;
  else { blk -= a.nblk;
  if (blk < b.nblk) p = b;
  else { blk -= b.nblk;
  if (blk < c.nblk) p = c;
  else { blk -= c.nblk;
  if (blk < d.nblk) p = d;
  else { blk -= d.nblk;
  if (blk < e.nblk) p = e;
  else { blk -= e.nblk; p = f; } } } } }
  const int bx = (blk % p.gw) * 32, by = (blk / p.gw) * 32;
  __shared__ float t[32][33];
  const int tx = threadIdx.x & 31, ty = threadIdx.x >> 5;
#pragma unroll
  for (int j = 0; j < 32; j += 8)
    t[ty + j][tx] = p.src[(long)(by + ty + j) * p.C + bx + tx];
  __syncthreads();
#pragma unroll
  for (int j = 0; j < 32; j += 8)
    p.dst[(long)(bx + ty + j) * p.R + by + tx] = __float2bfloat16(t[tx][ty + j]);
}

// rope (blocks < ropeBlks; q/k cols h*192+128..191, all < HQK) + V transpose
// (reads kvf cols >= HQK — disjoint from rope writes), one launch.
__global__ __launch_bounds__(256) void rope_vt_fused(
    bf16* __restrict__ q, bf16* __restrict__ k,
    const bf16* __restrict__ vsrc,  // kvf + HQK, stride NKV
    bf16* __restrict__ vT, int ropeBlks)
{
  int blk = blockIdx.x;
  if (blk < ropeBlks) {
    const int idx = blk * 256 + threadIdx.x;  // SEQ*NHEADS*32 threads
    const int i = idx & 31;
    const int h = (idx >> 5) & 15;
    const int l = idx >> 9;
    const float inv = powf(10000.f, -(float)i * (1.f / 32.f));
    float s, c;
    sincosf((float)l * inv, &s, &c);
    const long qb = (long)l * HQK + h * DQKC + 128;
    const long kb = (long)l * NKV + h * DQKC + 128;
    {
      float x0 = __bfloat162float(q[qb + i]);
      float x1 = __bfloat162float(q[qb + i + 32]);
      q[qb + i] = __float2bfloat16(x0 * c - x1 * s);
      q[qb + i + 32] = __float2bfloat16(x1 * c + x0 * s);
    }
    {
      float x0 = __bfloat162float(k[kb + i]);
      float x1 = __bfloat162float(k[kb + i + 32]);
      k[kb + i] = __float2bfloat16(x0 * c - x1 * s);
      k[kb + i + 32] = __float2bfloat16(x1 * c + x0 * s);
    }
    return;
  }
  blk -= ropeBlks;
  const int bx = (blk & 63) * 32, by = (blk >> 6) * 32;  // gw = HV/32 = 64
  __shared__ float t[32][33];
  const int tx = threadIdx.x & 31, ty = threadIdx.x >> 5;
#pragma unroll
  for (int j = 0; j < 32; j += 8)
    t[ty + j][tx] = __bfloat162float(vsrc[(long)(by + ty + j) * NKV + bx + tx]);
  __syncthreads();
#pragma unroll
  for (int j = 0; j < 32; j += 8)
    vT[(long)(bx + ty + j) * SEQ + by + tx] = __float2bfloat16(t[tx][ty + j]);
}

extern "C" void kernel_launch(void* const* d_in, const int* in_sizes, int n_in,
                              void* d_out, int out_size, void* d_ws, size_t ws_size,
                              hipStream_t stream) {
  const float* hs      = (const float*)d_in[0];
  // d_in[1] attention_mask: exact causal mask; applied analytically.
  const float* Wq_down = (const float*)d_in[2];
  const float* Wq_up   = (const float*)d_in[3];
  const float* Wkv_down= (const float*)d_in[4];
  const float* Wk_up   = (const float*)d_in[5];
  const float* Wv_up   = (const float*)d_in[6];
  const float* Wo      = (const float*)d_in[7];

  char* p = (char*)d_ws;
  auto alloc = [&](long elems) {
    bf16* r = (bf16*)p;
    p += ((elems * 2 + 255) / 256) * 256;
    return r;
  };
  bf16* hsb   = alloc((long)SEQ * DMODEL);
  bf16* W1T   = alloc((long)NDOWN * DMODEL);
  bf16* WquT  = alloc((long)HQK * DQC);
  bf16* WkvuT = alloc((long)NKV * DCC);
  bf16* WoT   = alloc((long)DMODEL * HV);
  bf16* qdc   = alloc((long)SEQ * NDOWN);
  bf16* qf    = alloc((long)SEQ * HQK);
  bf16* kvf   = alloc((long)SEQ * NKV);
  bf16* vT    = alloc((long)HV * SEQ);
  bf16* attn  = alloc((long)SEQ * HV);

  const float scale = 0.07216878364870323f;  // 1/sqrt(192), folded into q

  const dim3 b256(256);
  TPar ta{Wq_down,  W1T,                      DQC,    DMODEL, DQC / 32,    (DQC / 32) * (DMODEL / 32)};
  TPar tb2{Wkv_down, W1T + (long)DQC * DMODEL, DCC,    DMODEL, DCC / 32,    (DCC / 32) * (DMODEL / 32)};
  TPar tc{Wq_up,    WquT,                     HQK,    DQC,    HQK / 32,    (HQK / 32) * (DQC / 32)};
  TPar td{Wk_up,    WkvuT,                    HQK,    DCC,    HQK / 32,    (HQK / 32) * (DCC / 32)};
  TPar te{Wv_up,    WkvuT + (long)HQK * DCC,  HV,     DCC,    HV / 32,     (HV / 32) * (DCC / 32)};
  TPar tf{Wo,       WoT,                      DMODEL, HV,     DMODEL / 32, (DMODEL / 32) * (HV / 32)};
  const int tblk = ta.nblk + tb2.nblk + tc.nblk + td.nblk + te.nblk + tf.nblk;
  const int castBlks = SEQ * DMODEL / 4 / 256;
  prep_fused<<<dim3(castBlks + tblk), b256, 0, stream>>>(
      hs, hsb, SEQ * DMODEL / 4, castBlks, ta, tb2, tc, td, te, tf);

  // fused down-projection: [qd | ckv] = hsb @ [Wq_down | Wkv_down], 64x128
  gemm64<<<dim3(NDOWN / 128, SEQ / 64), b256, 0, stream>>>(
      hsb, DMODEL, W1T, DMODEL, qdc, NDOWN, DMODEL, 1.f, 0);

  // q up (scale folded) + fused k/v up, 128x128 tiles, contiguous split (R10)
  gemm_dual<<<dim3(HQK / 128 + NKV / 128, SEQ / 128), b256, 0, stream>>>(
      qdc, NDOWN, WquT, DQC, qf, HQK, DQC, scale, HQK / 128,
      qdc + DQC, NDOWN, WkvuT, DCC, kvf, NKV, DCC);

  // rope (q,k) + V transpose, one launch
  const int ropeBlks = SEQ * NHEADS * 32 / 256;
  rope_vt_fused<<<dim3(ropeBlks + (HV / 32) * (SEQ / 32)), b256, 0, stream>>>(
      qf, kvf, kvf + HQK, vT, ropeBlks);

  // fused attention v6.1: 512 blocks x 512 thr, kt-parity wave groups
  flash_attn<<<dim3(512), dim3(512), 0, stream>>>(qf, kvf, vT, attn);

  // output projection (fp32 out), 64x128
  gemm64<<<dim3(DMODEL / 128, SEQ / 64), b256, 0, stream>>>(
      attn, HV, WoT, HV, d_out, DMODEL, HV, 1.f, 1);
}